// Round 7
// baseline (200.633 us; speedup 1.0000x reference)
//
#include <hip/hip_runtime.h>
#include <math.h>

// Problem constants (B=16, C=64, H=W=128)
#define NB 16
#define CC 64
#define HH 128
#define WW 128
#define NPIX (NB*CC*HH*WW)       // 16777216
#define WELEM (CC*CC*9)          // 36864

// conv tiling: 16 rows x 32 cols output per block, all 64 oc. halo 18x34.
#define TR 16
#define TC 32
#define HR 18
#define HC 34
#define HPX (HR*HC)              // 612 halo pixels
#define PL  (HH*WW)              // plane stride

// padded quantized-x tensor: [n][132 rows][130 cols][64 ic] int8
// padded row r <-> image y = r-1 ; padded col c <-> image x = c-1
#define PYY 132
#define PXX 130
#define XQIMG (PYY*PXX*64)       // 1098240 B per image
#define XQTOT (NB*XQIMG)         // 17571840 B

typedef __attribute__((ext_vector_type(4))) int   int32x4;
typedef __attribute__((ext_vector_type(4))) short short4_t;

// LDS activation layout (conv2 only): [pix][64B], 16B chunks XOR-swizzled.
__device__ __forceinline__ int lds_a(int pix, int q) {
    return pix * 64 + ((q ^ ((pix >> 1) & 3)) << 4);
}

// ---------------- kernel 1: fused global max|x| + DoReFa weight quant ----------------
__global__ __launch_bounds__(1024) void k_reduce(const float* __restrict__ x,
                                                 const float* __restrict__ w1,
                                                 const float* __restrict__ w2,
                                                 unsigned* __restrict__ scal,
                                                 signed char* __restrict__ o1,
                                                 signed char* __restrict__ o2) {
    __shared__ float red[16];
    const int tid = threadIdx.x;
    if (blockIdx.x < 256) {
        const float4* x4 = (const float4*)x;
        const int n4 = NPIX / 4;
        float m = 0.f;
        for (int j = blockIdx.x * 1024 + tid; j < n4; j += 256 * 1024) {
            float4 v = x4[j];
            m = fmaxf(fmaxf(fabsf(v.x), fabsf(v.y)),
                      fmaxf(fmaxf(fabsf(v.z), fabsf(v.w)), m));
        }
        #pragma unroll
        for (int o = 32; o; o >>= 1) m = fmaxf(m, __shfl_down(m, o, 64));
        if ((tid & 63) == 0) red[tid >> 6] = m;
        __syncthreads();
        if (tid == 0) {
            float v = red[0];
            #pragma unroll
            for (int i = 1; i < 16; ++i) v = fmaxf(v, red[i]);
            atomicMax(scal, __float_as_uint(v));
        }
    } else {
        const float* __restrict__ w = (blockIdx.x == 257) ? w2 : w1;
        signed char* __restrict__ w8 = (blockIdx.x == 257) ? o2 : o1;
        float m = 0.f;
        for (int i = tid; i < WELEM; i += 1024) m = fmaxf(m, fabsf(tanhf(w[i])));
        #pragma unroll
        for (int o = 32; o; o >>= 1) m = fmaxf(m, __shfl_down(m, o, 64));
        if ((tid & 63) == 0) red[tid >> 6] = m;
        __syncthreads();
        float mx = 0.f;
        #pragma unroll
        for (int i = 0; i < 16; ++i) mx = fmaxf(mx, red[i]);
        float inv = 1.f / (mx + 1e-8f);
        for (int i = tid; i < WELEM; i += 1024) {
            float wt = tanhf(w[i]) * inv;                 // [-1, 1]
            float r  = rintf((wt + 1.f) * 1.5f);          // 0..3 (round-half-even)
            int oc = i / 576, rem = i % 576, ic = rem / 9, tap = rem % 9;
            // B-fragment: lane = (oc&15) | ((ic>>4)<<4); k-byte = ic&15
            int lane2 = (oc & 15) | ((ic >> 4) << 4);
            w8[(((oc >> 4) * 9 + tap) * 64 + lane2) * 16 + (ic & 15)] =
                (signed char)(int)(2.f * r - 3.f);
        }
    }
}

// ---------------- kernel 1b: quantize x -> padded pixel-major int8 ----------------
__global__ __launch_bounds__(256) void k_quantx(const float* __restrict__ x,
                                                const unsigned* __restrict__ scal,
                                                signed char* __restrict__ xq) {
    __shared__ signed char ldsA[64 * 68];
    __shared__ int ldsB[64 * 16];
    const int tid = threadIdx.x;
    const int n = blockIdx.z, y = blockIdx.y, s = blockIdx.x;
    const float inv_s1 = 1.f / (__uint_as_float(scal[0]) + 1e-8f);

    {
        const int ic = tid >> 2, g = tid & 3;
        const float* __restrict__ src =
            x + (((size_t)n * CC + ic) * HH + y) * WW + s * 64 + g * 16;
        unsigned dw[4];
        #pragma unroll
        for (int q = 0; q < 4; ++q) {
            float4 v = *(const float4*)(src + q * 4);
            float e[4] = {v.x, v.y, v.z, v.w};
            unsigned d = 0;
            #pragma unroll
            for (int j = 0; j < 4; ++j) {
                int qq = (int)rintf(fminf(fmaxf(e[j] * inv_s1, -1.f), 1.f));
                d |= (unsigned)(qq & 255) << (8 * j);
            }
            dw[q] = d;
        }
        *(int4*)(ldsA + ic * 68 + g * 16) = *(const int4*)dw;
    }
    __syncthreads();
    #pragma unroll
    for (int i = 0; i < 4; ++i) {
        int idx = tid + i * 256;
        int d = idx & 15, p = idx >> 4;
        const signed char* a = ldsA + (d * 4) * 68 + p;
        unsigned b0 = (unsigned char)a[0];
        unsigned b1 = (unsigned char)a[68];
        unsigned b2 = (unsigned char)a[136];
        unsigned b3 = (unsigned char)a[204];
        ldsB[p * 16 + d] = (int)(b0 | (b1 << 8) | (b2 << 16) | (b3 << 24));
    }
    __syncthreads();
    signed char* dst = xq + ((size_t)n * PYY + (y + 1)) * (PXX * 64)
                          + (size_t)(1 + s * 64) * 64;
    ((int4*)dst)[tid] = ((const int4*)ldsB)[tid];
}

// ---------------- conv1: barrier-free streaming MFMA (no LDS operands) ----------------
// A-fragment = contiguous 1KB/wave directly from padded xq; B from global (L1-hit).
__global__ __launch_bounds__(512, 4) void k_conv1(
    const signed char* __restrict__ xq,
    const signed char* __restrict__ w8,
    const float* __restrict__ bias,       // b1 (for relu-max only)
    unsigned* __restrict__ scal,
    short* __restrict__ accout)
{
    __shared__ float redm[8];
    const int tid = threadIdx.x;
    const int n   = blockIdx.z;
    const int oy0 = blockIdx.y * TR;
    const int ox0 = blockIdx.x * TC;
    const float s1 = __uint_as_float(scal[0]) + 1e-8f;

    const int w     = tid >> 6;
    const int lane  = tid & 63;
    const int lq    = lane >> 4;
    const int lc    = lane & 15;
    const int mH    = w & 1;
    const int rbase = (w >> 1) * 4;

    // per-lane base: pixel (oy0+rbase, ox0+lc), chunk lq
    const signed char* __restrict__ A0 = xq + (size_t)n * XQIMG
        + ((size_t)(oy0 + rbase) * PXX + ox0 + lc) * 64 + lq * 16;
    const signed char* __restrict__ W0 = w8 + ((size_t)mH * 18 * 64 + lane) * 16;

    int32x4 acc0[8] = {};
    int32x4 acc1[8] = {};
    #pragma unroll 3
    for (int tap = 0; tap < 9; ++tap) {
        const int ky = tap / 3, kx = tap % 3;
        int32x4 b0 = *(const int32x4*)(W0 + (size_t)tap * 1024);
        int32x4 b1 = *(const int32x4*)(W0 + (size_t)(9 + tap) * 1024);
        const signed char* ar = A0 + (ky * PXX + kx) * 64;
        #pragma unroll
        for (int j = 0; j < 8; ++j) {
            int32x4 a = *(const int32x4*)(ar + ((j >> 1) * PXX + ((j & 1) << 4)) * 64);
            acc0[j] = __builtin_amdgcn_mfma_i32_16x16x64_i8(a, b0, acc0[j], 0, 0, 0);
            acc1[j] = __builtin_amdgcn_mfma_i32_16x16x64_i8(a, b1, acc1[j], 0, 0, 0);
        }
    }

    // epilogue: int16 acc store + slotted atomic relu-max
    const float sc = s1 * (1.f / 3.f);
    const int oc0 = mH * 32 + lc;
    const int oc1 = oc0 + 16;
    const float bo0 = bias[oc0], bo1 = bias[oc1];
    const size_t imgbase = (size_t)n * CC * PL;

    float m2 = 0.f;
    #pragma unroll
    for (int j = 0; j < 8; ++j) {
        int yy = oy0 + rbase + (j >> 1);
        int xb = ox0 + ((j & 1) << 4) + lq * 4;
        size_t p0 = imgbase + (size_t)oc0 * PL + yy * WW + xb;
        size_t p1 = imgbase + (size_t)oc1 * PL + yy * WW + xb;
        short4_t s0, s1v;
        #pragma unroll
        for (int g = 0; g < 4; ++g) {
            s0[g]  = (short)acc0[j][g];
            s1v[g] = (short)acc1[j][g];
            m2 = fmaxf(m2, sc * (float)acc0[j][g] + bo0);
            m2 = fmaxf(m2, sc * (float)acc1[j][g] + bo1);
        }
        *(short4_t*)(accout + p0) = s0;
        *(short4_t*)(accout + p1) = s1v;
    }
    #pragma unroll
    for (int o = 32; o; o >>= 1) m2 = fmaxf(m2, __shfl_down(m2, o, 64));
    if (lane == 0) redm[w] = m2;
    __syncthreads();
    if (tid == 0) {
        float v = redm[0];
        #pragma unroll
        for (int i = 1; i < 8; ++i) v = fmaxf(v, redm[i]);
        int slot = (blockIdx.x + blockIdx.y * 4 + blockIdx.z) & 7;
        atomicMax(&scal[64 + slot * 32], __float_as_uint(v));
    }
}

// ---------------- conv2: binarize-stage (LDS) + MFMA (global weights) ----------------
__global__ __launch_bounds__(512, 6) void k_conv2(
    const float* __restrict__ x,
    const short* __restrict__ accin,
    const signed char* __restrict__ w8,
    const float* __restrict__ bias,       // b2
    const float* __restrict__ b1v,        // b1 (dequant of acc)
    const unsigned* __restrict__ scal,
    float* __restrict__ out)
{
    __shared__ signed char sA[HPX * 64] __attribute__((aligned(16)));   // 39168 B

    const int tid = threadIdx.x;
    const int n   = blockIdx.z;
    const int oy0 = blockIdx.y * TR;
    const int ox0 = blockIdx.x * TC;

    const float s1 = __uint_as_float(scal[0]) + 1e-8f;
    float mx = 0.f;
    #pragma unroll
    for (int i = 0; i < 8; ++i) mx = fmaxf(mx, __uint_as_float(scal[64 + i * 32]));
    const float s2v = mx + 1e-8f;
    const float half_s2 = 0.5f * s2v;
    const float sc1 = s1 * (1.f / 3.f);

    // stage + binarize halo: tasks = (row r, aligned 4px group cg, ic4)
    for (int t = tid; t < HR * 10 * 16; t += 512) {
        const int ic4 = t / (HR * 10);
        const int rcg = t - ic4 * (HR * 10);
        const int r   = rcg / 10;
        const int cg  = rcg - r * 10;
        const int y   = oy0 - 1 + r;
        const int ry  = (y >= 0) & (y < HH);
        const int yc  = min(max(y, 0), HH - 1);
        const int xx0 = ox0 - 4 + cg * 4;
        const int vg  = ry & (xx0 >= 0) & (xx0 < WW);
        const int xc0 = min(max(xx0, 0), WW - 4);

        unsigned pk[4] = {0, 0, 0, 0};
        const short* __restrict__ ap =
            accin + ((size_t)n * CC + ic4 * 4) * PL + yc * WW + xc0;
        float4 b4 = *(const float4*)(b1v + ic4 * 4);
        float bb[4] = {b4.x, b4.y, b4.z, b4.w};
        #pragma unroll
        for (int j = 0; j < 4; ++j) {
            short4_t v = *(const short4_t*)(ap + (size_t)j * PL);
            #pragma unroll
            for (int i = 0; i < 4; ++i) {
                float e = sc1 * (float)v[i] + bb[j];
                if (e >= half_s2) pk[i] |= 1u << (8 * j);
            }
        }
        const int lo = (ic4 & 3) * 4;
        #pragma unroll
        for (int i = 0; i < 4; ++i) {
            int c = cg * 4 - 3 + i;
            if (c >= 0 && c < HC) {
                int pix = r * HC + c;
                *(int*)(sA + lds_a(pix, ic4 >> 2) + lo) = vg ? (int)pk[i] : 0;
            }
        }
    }
    __syncthreads();

    const int w     = tid >> 6;
    const int lane  = tid & 63;
    const int lq    = lane >> 4;
    const int lc    = lane & 15;
    const int mH    = w & 1;
    const int rbase = (w >> 1) * 4;
    const signed char* __restrict__ W0 = w8 + ((size_t)mH * 18 * 64 + lane) * 16;

    int32x4 acc0[8] = {};
    int32x4 acc1[8] = {};
    __builtin_amdgcn_s_setprio(1);
    #pragma unroll 3
    for (int tap = 0; tap < 9; ++tap) {
        const int ky = tap / 3, kx = tap % 3;
        int32x4 b0 = *(const int32x4*)(W0 + (size_t)tap * 1024);
        int32x4 b1 = *(const int32x4*)(W0 + (size_t)(9 + tap) * 1024);
        const int pbase = (rbase + ky) * HC + kx + lc;
        #pragma unroll
        for (int j = 0; j < 8; ++j) {
            int pix = pbase + (j >> 1) * HC + ((j & 1) << 4);
            int32x4 a = *(const int32x4*)(sA + lds_a(pix, lq));
            acc0[j] = __builtin_amdgcn_mfma_i32_16x16x64_i8(a, b0, acc0[j], 0, 0, 0);
            acc1[j] = __builtin_amdgcn_mfma_i32_16x16x64_i8(a, b1, acc1[j], 0, 0, 0);
        }
    }
    __builtin_amdgcn_s_setprio(0);

    const float sc = s2v * (1.f / 3.f);
    const int oc0 = mH * 32 + lc;
    const int oc1 = oc0 + 16;
    const float bo0 = bias[oc0], bo1 = bias[oc1];
    const size_t imgbase = (size_t)n * CC * PL;

    #pragma unroll
    for (int j = 0; j < 8; ++j) {
        int yy = oy0 + rbase + (j >> 1);
        int xb = ox0 + ((j & 1) << 4) + lq * 4;
        size_t p0 = imgbase + (size_t)oc0 * PL + yy * WW + xb;
        size_t p1 = imgbase + (size_t)oc1 * PL + yy * WW + xb;
        float4 xa  = *(const float4*)(x + p0);
        float4 xb4 = *(const float4*)(x + p1);
        float4 r0, r1;
        r0.x = sc * (float)acc0[j][0] + bo0 + xa.x;
        r0.y = sc * (float)acc0[j][1] + bo0 + xa.y;
        r0.z = sc * (float)acc0[j][2] + bo0 + xa.z;
        r0.w = sc * (float)acc0[j][3] + bo0 + xa.w;
        r1.x = sc * (float)acc1[j][0] + bo1 + xb4.x;
        r1.y = sc * (float)acc1[j][1] + bo1 + xb4.y;
        r1.z = sc * (float)acc1[j][2] + bo1 + xb4.z;
        r1.w = sc * (float)acc1[j][3] + bo1 + xb4.w;
        *(float4*)(out + p0) = r0;
        *(float4*)(out + p1) = r1;
    }
}

extern "C" void kernel_launch(void* const* d_in, const int* in_sizes, int n_in,
                              void* d_out, int out_size, void* d_ws, size_t ws_size,
                              hipStream_t stream) {
    const float* x  = (const float*)d_in[0];
    const float* w1 = (const float*)d_in[1];
    const float* b1 = (const float*)d_in[2];
    const float* w2 = (const float*)d_in[3];
    const float* b2 = (const float*)d_in[4];
    float* out = (float*)d_out;

    // ws layout
    unsigned*    scal  = (unsigned*)d_ws;                  // [0]=s1; s2 slots at [64+i*32]
    signed char* w8_1  = (signed char*)d_ws + 2048;        // 36864 B
    signed char* w8_2  = w8_1 + WELEM;                     // 36864 B
    short*       acc16 = (short*)((char*)d_ws + 131072);   // 33.5 MB
    // xq lives in d_out's scratch space: written by k_quantx, read only by
    // k_conv1, fully overwritten by k_conv2's final output.
    signed char* xq    = (signed char*)d_out;

    hipMemsetAsync(d_ws, 0, 2048, stream);
    hipMemsetAsync(d_out, 0, XQTOT, stream);   // zero padded borders of xq

    k_reduce<<<258, 1024, 0, stream>>>(x, w1, w2, scal, w8_1, w8_2);
    k_quantx<<<dim3(2, HH, NB), 256, 0, stream>>>(x, scal, xq);

    dim3 grid(WW / TC, HH / TR, NB);   // (4, 8, 16)
    k_conv1<<<grid, 512, 0, stream>>>(xq, w8_1, b1, scal, acc16);
    k_conv2<<<grid, 512, 0, stream>>>(x, acc16, w8_2, b2, b1, scal, out);
}

// Round 8
// 156.376 us; speedup vs baseline: 1.2830x; 1.2830x over previous
//
#include <hip/hip_runtime.h>
#include <math.h>

// Problem constants (B=16, C=64, H=W=128)
#define NB 16
#define CC 64
#define HH 128
#define WW 128
#define NPIX (NB*CC*HH*WW)       // 16777216
#define WELEM (CC*CC*9)          // 36864

// conv tiling: 16x16 output px per block, all 64 oc. halo 18x18.
#define TR 16
#define TC 16
#define HR 18
#define HC 18
#define HPX (HR*HC)              // 324 halo pixels
#define PL  (HH*WW)              // plane stride

// padded quantized-x tensor: [n][132 rows][130 cols][64 ic] int8
#define PYY 132
#define PXX 130
#define XQIMG (PYY*PXX*64)       // 1098240 B per image
#define XQTOT (NB*XQIMG)         // 17571840 B

typedef __attribute__((ext_vector_type(4))) int   int32x4;
typedef __attribute__((ext_vector_type(4))) short short4_t;

// LDS activation layout (conv2): [pix][64B], 16B chunks XOR-swizzled.
__device__ __forceinline__ int lds_a(int pix, int q) {
    return pix * 64 + ((q ^ ((pix >> 1) & 3)) << 4);
}

// ---------------- kernel 1: fused global max|x| + DoReFa weight quant ----------------
__global__ __launch_bounds__(1024) void k_reduce(const float* __restrict__ x,
                                                 const float* __restrict__ w1,
                                                 const float* __restrict__ w2,
                                                 unsigned* __restrict__ scal,
                                                 signed char* __restrict__ o1,
                                                 signed char* __restrict__ o2) {
    __shared__ float red[16];
    const int tid = threadIdx.x;
    if (blockIdx.x < 256) {
        const float4* x4 = (const float4*)x;
        const int n4 = NPIX / 4;
        float m = 0.f;
        for (int j = blockIdx.x * 1024 + tid; j < n4; j += 256 * 1024) {
            float4 v = x4[j];
            m = fmaxf(fmaxf(fabsf(v.x), fabsf(v.y)),
                      fmaxf(fmaxf(fabsf(v.z), fabsf(v.w)), m));
        }
        #pragma unroll
        for (int o = 32; o; o >>= 1) m = fmaxf(m, __shfl_down(m, o, 64));
        if ((tid & 63) == 0) red[tid >> 6] = m;
        __syncthreads();
        if (tid == 0) {
            float v = red[0];
            #pragma unroll
            for (int i = 1; i < 16; ++i) v = fmaxf(v, red[i]);
            atomicMax(scal, __float_as_uint(v));
        }
    } else {
        const float* __restrict__ w = (blockIdx.x == 257) ? w2 : w1;
        signed char* __restrict__ w8 = (blockIdx.x == 257) ? o2 : o1;
        float m = 0.f;
        for (int i = tid; i < WELEM; i += 1024) m = fmaxf(m, fabsf(tanhf(w[i])));
        #pragma unroll
        for (int o = 32; o; o >>= 1) m = fmaxf(m, __shfl_down(m, o, 64));
        if ((tid & 63) == 0) red[tid >> 6] = m;
        __syncthreads();
        float mx = 0.f;
        #pragma unroll
        for (int i = 0; i < 16; ++i) mx = fmaxf(mx, red[i]);
        float inv = 1.f / (mx + 1e-8f);
        for (int i = tid; i < WELEM; i += 1024) {
            float wt = tanhf(w[i]) * inv;                 // [-1, 1]
            float r  = rintf((wt + 1.f) * 1.5f);          // 0..3 (round-half-even)
            int oc = i / 576, rem = i % 576, ic = rem / 9, tap = rem % 9;
            // fragment: lane = (oc&15) | ((ic>>4)<<4); k-byte = ic&15
            int lane2 = (oc & 15) | ((ic >> 4) << 4);
            w8[(((oc >> 4) * 9 + tap) * 64 + lane2) * 16 + (ic & 15)] =
                (signed char)(int)(2.f * r - 3.f);
        }
    }
}

// ---------------- kernel 1b: quantize x -> padded pixel-major int8 ----------------
__global__ __launch_bounds__(256) void k_quantx(const float* __restrict__ x,
                                                const unsigned* __restrict__ scal,
                                                signed char* __restrict__ xq) {
    __shared__ signed char ldsA[64 * 68];
    __shared__ int ldsB[64 * 16];
    const int tid = threadIdx.x;
    const int n = blockIdx.z, y = blockIdx.y, s = blockIdx.x;
    const float inv_s1 = 1.f / (__uint_as_float(scal[0]) + 1e-8f);

    {
        const int ic = tid >> 2, g = tid & 3;
        const float* __restrict__ src =
            x + (((size_t)n * CC + ic) * HH + y) * WW + s * 64 + g * 16;
        unsigned dw[4];
        #pragma unroll
        for (int q = 0; q < 4; ++q) {
            float4 v = *(const float4*)(src + q * 4);
            float e[4] = {v.x, v.y, v.z, v.w};
            unsigned d = 0;
            #pragma unroll
            for (int j = 0; j < 4; ++j) {
                int qq = (int)rintf(fminf(fmaxf(e[j] * inv_s1, -1.f), 1.f));
                d |= (unsigned)(qq & 255) << (8 * j);
            }
            dw[q] = d;
        }
        *(int4*)(ldsA + ic * 68 + g * 16) = *(const int4*)dw;
    }
    __syncthreads();
    #pragma unroll
    for (int i = 0; i < 4; ++i) {
        int idx = tid + i * 256;
        int d = idx & 15, p = idx >> 4;
        const signed char* a = ldsA + (d * 4) * 68 + p;
        unsigned b0 = (unsigned char)a[0];
        unsigned b1 = (unsigned char)a[68];
        unsigned b2 = (unsigned char)a[136];
        unsigned b3 = (unsigned char)a[204];
        ldsB[p * 16 + d] = (int)(b0 | (b1 << 8) | (b2 << 16) | (b3 << 24));
    }
    __syncthreads();
    signed char* dst = xq + ((size_t)n * PYY + (y + 1)) * (PXX * 64)
                          + (size_t)(1 + s * 64) * 64;
    ((int4*)dst)[tid] = ((const int4*)ldsB)[tid];
}

// ---------------- conv1: barrier-free streaming MFMA (no LDS operands) ----------------
// A = activations (M = 16 consecutive x), B = weights (N = 16 oc).
// Per wave: J=4 pixel-frags (4 rows x 16 cols) x O=2 oc-frags -> acc = 32 VGPR.
__global__ __launch_bounds__(512, 5) void k_conv1(
    const signed char* __restrict__ xq,
    const signed char* __restrict__ w8,
    const float* __restrict__ bias,       // b1 (for relu-max only)
    unsigned* __restrict__ scal,
    short* __restrict__ accout)
{
    __shared__ float redm[8];
    const int tid = threadIdx.x;
    const int n   = blockIdx.z;
    const int oy0 = blockIdx.y * TR;
    const int ox0 = blockIdx.x * TC;
    const float s1 = __uint_as_float(scal[0]) + 1e-8f;

    const int w     = tid >> 6;
    const int lane  = tid & 63;
    const int lq    = lane >> 4;
    const int lc    = lane & 15;
    const int mH    = w & 1;
    const int rbase = (w >> 1) * 4;       // 4 row-bands x 4 rows = 16 rows

    const signed char* __restrict__ A0 = xq + (size_t)n * XQIMG
        + ((size_t)(oy0 + rbase) * PXX + ox0 + lc) * 64 + lq * 16;
    const signed char* __restrict__ W0 = w8 + ((size_t)mH * 18 * 64 + lane) * 16;

    int32x4 acc0[4] = {};
    int32x4 acc1[4] = {};
    #pragma unroll 3
    for (int tap = 0; tap < 9; ++tap) {
        const int ky = tap / 3, kx = tap % 3;
        int32x4 b0 = *(const int32x4*)(W0 + (size_t)tap * 1024);
        int32x4 b1 = *(const int32x4*)(W0 + (size_t)(9 + tap) * 1024);
        const signed char* ar = A0 + (ky * PXX + kx) * 64;
        #pragma unroll
        for (int j = 0; j < 4; ++j) {
            int32x4 a = *(const int32x4*)(ar + j * (PXX * 64));
            acc0[j] = __builtin_amdgcn_mfma_i32_16x16x64_i8(a, b0, acc0[j], 0, 0, 0);
            acc1[j] = __builtin_amdgcn_mfma_i32_16x16x64_i8(a, b1, acc1[j], 0, 0, 0);
        }
    }

    // epilogue: int16 acc store + slotted atomic relu-max
    const float sc = s1 * (1.f / 3.f);
    const int oc0 = mH * 32 + lc;
    const int oc1 = oc0 + 16;
    const float bo0 = bias[oc0], bo1 = bias[oc1];
    const size_t imgbase = (size_t)n * CC * PL;

    float m2 = 0.f;
    #pragma unroll
    for (int j = 0; j < 4; ++j) {
        int yy = oy0 + rbase + j;
        int xb = ox0 + lq * 4;
        size_t p0 = imgbase + (size_t)oc0 * PL + yy * WW + xb;
        size_t p1 = imgbase + (size_t)oc1 * PL + yy * WW + xb;
        short4_t s0, s1v;
        #pragma unroll
        for (int g = 0; g < 4; ++g) {
            s0[g]  = (short)acc0[j][g];
            s1v[g] = (short)acc1[j][g];
            m2 = fmaxf(m2, sc * (float)acc0[j][g] + bo0);
            m2 = fmaxf(m2, sc * (float)acc1[j][g] + bo1);
        }
        *(short4_t*)(accout + p0) = s0;
        *(short4_t*)(accout + p1) = s1v;
    }
    #pragma unroll
    for (int o = 32; o; o >>= 1) m2 = fmaxf(m2, __shfl_down(m2, o, 64));
    if (lane == 0) redm[w] = m2;
    __syncthreads();
    if (tid == 0) {
        float v = redm[0];
        #pragma unroll
        for (int i = 1; i < 8; ++i) v = fmaxf(v, redm[i]);
        int slot = (blockIdx.x + blockIdx.y * 8 + blockIdx.z) & 7;
        atomicMax(&scal[64 + slot * 32], __float_as_uint(v));
    }
}

// ---------------- conv2: binarize-stage (LDS) + MFMA (global weights) ----------------
__global__ __launch_bounds__(512, 5) void k_conv2(
    const float* __restrict__ x,
    const short* __restrict__ accin,
    const signed char* __restrict__ w8,
    const float* __restrict__ bias,       // b2
    const float* __restrict__ b1v,        // b1 (dequant of acc)
    const unsigned* __restrict__ scal,
    float* __restrict__ out)
{
    __shared__ signed char sA[HPX * 64] __attribute__((aligned(16)));   // 20736 B

    const int tid = threadIdx.x;
    const int n   = blockIdx.z;
    const int oy0 = blockIdx.y * TR;
    const int ox0 = blockIdx.x * TC;

    const float s1 = __uint_as_float(scal[0]) + 1e-8f;
    float mx = 0.f;
    #pragma unroll
    for (int i = 0; i < 8; ++i) mx = fmaxf(mx, __uint_as_float(scal[64 + i * 32]));
    const float s2v = mx + 1e-8f;
    const float half_s2 = 0.5f * s2v;
    const float sc1 = s1 * (1.f / 3.f);

    // stage + binarize halo: tasks = (row r 0..17, 4px group cg 0..5, ic4 0..15)
    for (int t = tid; t < HR * 6 * 16; t += 512) {
        const int ic4 = t / (HR * 6);
        const int rcg = t - ic4 * (HR * 6);
        const int r   = rcg / 6;
        const int cg  = rcg - r * 6;
        const int y   = oy0 - 1 + r;
        const int ry  = (y >= 0) & (y < HH);
        const int yc  = min(max(y, 0), HH - 1);
        const int xx0 = ox0 - 4 + cg * 4;
        const int vg  = ry & (xx0 >= 0) & (xx0 < WW);
        const int xc0 = min(max(xx0, 0), WW - 4);

        unsigned pk[4] = {0, 0, 0, 0};
        const short* __restrict__ ap =
            accin + ((size_t)n * CC + ic4 * 4) * PL + yc * WW + xc0;
        float4 b4 = *(const float4*)(b1v + ic4 * 4);
        float bb[4] = {b4.x, b4.y, b4.z, b4.w};
        #pragma unroll
        for (int j = 0; j < 4; ++j) {
            short4_t v = *(const short4_t*)(ap + (size_t)j * PL);
            #pragma unroll
            for (int i = 0; i < 4; ++i) {
                float e = sc1 * (float)v[i] + bb[j];
                if (e >= half_s2) pk[i] |= 1u << (8 * j);
            }
        }
        const int lo = (ic4 & 3) * 4;
        #pragma unroll
        for (int i = 0; i < 4; ++i) {
            int c = cg * 4 - 3 + i;
            if (c >= 0 && c < HC) {
                int pix = r * HC + c;
                *(int*)(sA + lds_a(pix, ic4 >> 2) + lo) = vg ? (int)pk[i] : 0;
            }
        }
    }
    __syncthreads();

    const int w     = tid >> 6;
    const int lane  = tid & 63;
    const int lq    = lane >> 4;
    const int lc    = lane & 15;
    const int mH    = w & 1;
    const int rbase = (w >> 1) * 4;
    const signed char* __restrict__ W0 = w8 + ((size_t)mH * 18 * 64 + lane) * 16;

    int32x4 acc0[4] = {};
    int32x4 acc1[4] = {};
    __builtin_amdgcn_s_setprio(1);
    #pragma unroll 3
    for (int tap = 0; tap < 9; ++tap) {
        const int ky = tap / 3, kx = tap % 3;
        int32x4 b0 = *(const int32x4*)(W0 + (size_t)tap * 1024);
        int32x4 b1 = *(const int32x4*)(W0 + (size_t)(9 + tap) * 1024);
        #pragma unroll
        for (int j = 0; j < 4; ++j) {
            int pix = (rbase + j + ky) * HC + kx + lc;
            int32x4 a = *(const int32x4*)(sA + lds_a(pix, lq));
            acc0[j] = __builtin_amdgcn_mfma_i32_16x16x64_i8(a, b0, acc0[j], 0, 0, 0);
            acc1[j] = __builtin_amdgcn_mfma_i32_16x16x64_i8(a, b1, acc1[j], 0, 0, 0);
        }
    }
    __builtin_amdgcn_s_setprio(0);

    const float sc = s2v * (1.f / 3.f);
    const int oc0 = mH * 32 + lc;
    const int oc1 = oc0 + 16;
    const float bo0 = bias[oc0], bo1 = bias[oc1];
    const size_t imgbase = (size_t)n * CC * PL;

    #pragma unroll
    for (int j = 0; j < 4; ++j) {
        int yy = oy0 + rbase + j;
        int xb = ox0 + lq * 4;
        size_t p0 = imgbase + (size_t)oc0 * PL + yy * WW + xb;
        size_t p1 = imgbase + (size_t)oc1 * PL + yy * WW + xb;
        float4 xa  = *(const float4*)(x + p0);
        float4 xb4 = *(const float4*)(x + p1);
        float4 r0, r1;
        r0.x = sc * (float)acc0[j][0] + bo0 + xa.x;
        r0.y = sc * (float)acc0[j][1] + bo0 + xa.y;
        r0.z = sc * (float)acc0[j][2] + bo0 + xa.z;
        r0.w = sc * (float)acc0[j][3] + bo0 + xa.w;
        r1.x = sc * (float)acc1[j][0] + bo1 + xb4.x;
        r1.y = sc * (float)acc1[j][1] + bo1 + xb4.y;
        r1.z = sc * (float)acc1[j][2] + bo1 + xb4.z;
        r1.w = sc * (float)acc1[j][3] + bo1 + xb4.w;
        *(float4*)(out + p0) = r0;
        *(float4*)(out + p1) = r1;
    }
}

extern "C" void kernel_launch(void* const* d_in, const int* in_sizes, int n_in,
                              void* d_out, int out_size, void* d_ws, size_t ws_size,
                              hipStream_t stream) {
    const float* x  = (const float*)d_in[0];
    const float* w1 = (const float*)d_in[1];
    const float* b1 = (const float*)d_in[2];
    const float* w2 = (const float*)d_in[3];
    const float* b2 = (const float*)d_in[4];
    float* out = (float*)d_out;

    // ws layout
    unsigned*    scal  = (unsigned*)d_ws;                  // [0]=s1; s2 slots at [64+i*32]
    signed char* w8_1  = (signed char*)d_ws + 2048;        // 36864 B
    signed char* w8_2  = w8_1 + WELEM;                     // 36864 B
    short*       acc16 = (short*)((char*)d_ws + 131072);   // 33.5 MB
    // xq lives in d_out's scratch space: written by k_quantx, read only by
    // k_conv1, fully overwritten by k_conv2's final output.
    signed char* xq    = (signed char*)d_out;

    hipMemsetAsync(d_ws, 0, 2048, stream);
    hipMemsetAsync(d_out, 0, XQTOT, stream);   // zero padded borders of xq

    k_reduce<<<258, 1024, 0, stream>>>(x, w1, w2, scal, w8_1, w8_2);
    k_quantx<<<dim3(2, HH, NB), 256, 0, stream>>>(x, scal, xq);

    dim3 grid(WW / TC, HH / TR, NB);   // (8, 8, 16)
    k_conv1<<<grid, 512, 0, stream>>>(xq, w8_1, b1, scal, acc16);
    k_conv2<<<grid, 512, 0, stream>>>(x, acc16, w8_2, b2, b1, scal, out);
}

// Round 9
// 134.364 us; speedup vs baseline: 1.4932x; 1.1638x over previous
//
#include <hip/hip_runtime.h>
#include <math.h>

// Problem constants (B=16, C=64, H=W=128)
#define NB 16
#define CC 64
#define HH 128
#define WW 128
#define NPIX (NB*CC*HH*WW)       // 16777216
#define WELEM (CC*CC*9)          // 36864

// conv tiling: 16x16 output px per block, all 64 oc. halo 18x18.
#define TR 16
#define TC 16
#define HR 18
#define HC 18
#define HPX (HR*HC)              // 324 halo pixels
#define PL  (HH*WW)              // plane stride

// padded quantized-x tensor: [n][132 rows][130 cols][64 ic] int8
#define PYY 132
#define PXX 130
#define XQIMG (PYY*PXX*64)       // 1098240 B per image
#define XQTOT (NB*XQIMG)         // 17571840 B

typedef __attribute__((ext_vector_type(4))) int   int32x4;
typedef __attribute__((ext_vector_type(4))) short short4_t;
typedef __attribute__((ext_vector_type(8))) short short8_t;

// LDS activation layout (conv2): [pix][64B], 16B chunks XOR-swizzled.
__device__ __forceinline__ int lds_a(int pix, int q) {
    return pix * 64 + ((q ^ ((pix >> 1) & 3)) << 4);
}

// ---------------- kernel 1: fused global max|x| + DoReFa weight quant ----------------
__global__ __launch_bounds__(1024) void k_reduce(const float* __restrict__ x,
                                                 const float* __restrict__ w1,
                                                 const float* __restrict__ w2,
                                                 unsigned* __restrict__ scal,
                                                 signed char* __restrict__ o1,
                                                 signed char* __restrict__ o2) {
    __shared__ float red[16];
    const int tid = threadIdx.x;
    if (blockIdx.x < 256) {
        const float4* x4 = (const float4*)x;
        const int n4 = NPIX / 4;
        float m = 0.f;
        for (int j = blockIdx.x * 1024 + tid; j < n4; j += 256 * 1024) {
            float4 v = x4[j];
            m = fmaxf(fmaxf(fabsf(v.x), fabsf(v.y)),
                      fmaxf(fmaxf(fabsf(v.z), fabsf(v.w)), m));
        }
        #pragma unroll
        for (int o = 32; o; o >>= 1) m = fmaxf(m, __shfl_down(m, o, 64));
        if ((tid & 63) == 0) red[tid >> 6] = m;
        __syncthreads();
        if (tid == 0) {
            float v = red[0];
            #pragma unroll
            for (int i = 1; i < 16; ++i) v = fmaxf(v, red[i]);
            atomicMax(scal, __float_as_uint(v));
        }
    } else {
        const float* __restrict__ w = (blockIdx.x == 257) ? w2 : w1;
        signed char* __restrict__ w8 = (blockIdx.x == 257) ? o2 : o1;
        float m = 0.f;
        for (int i = tid; i < WELEM; i += 1024) m = fmaxf(m, fabsf(tanhf(w[i])));
        #pragma unroll
        for (int o = 32; o; o >>= 1) m = fmaxf(m, __shfl_down(m, o, 64));
        if ((tid & 63) == 0) red[tid >> 6] = m;
        __syncthreads();
        float mx = 0.f;
        #pragma unroll
        for (int i = 0; i < 16; ++i) mx = fmaxf(mx, red[i]);
        float inv = 1.f / (mx + 1e-8f);
        for (int i = tid; i < WELEM; i += 1024) {
            float wt = tanhf(w[i]) * inv;                 // [-1, 1]
            float r  = rintf((wt + 1.f) * 1.5f);          // 0..3 (round-half-even)
            int oc = i / 576, rem = i % 576, ic = rem / 9, tap = rem % 9;
            // fragment: lane = (oc&15) | ((ic>>4)<<4); k-byte = ic&15
            int lane2 = (oc & 15) | ((ic >> 4) << 4);
            w8[(((oc >> 4) * 9 + tap) * 64 + lane2) * 16 + (ic & 15)] =
                (signed char)(int)(2.f * r - 3.f);
        }
    }
}

// ---------------- kernel 1b: quantize x -> padded pixel-major int8 ----------------
__global__ __launch_bounds__(256) void k_quantx(const float* __restrict__ x,
                                                const unsigned* __restrict__ scal,
                                                signed char* __restrict__ xq) {
    __shared__ signed char ldsA[64 * 68];
    __shared__ int ldsB[64 * 16];
    const int tid = threadIdx.x;
    const int n = blockIdx.z, y = blockIdx.y, s = blockIdx.x;
    const float inv_s1 = 1.f / (__uint_as_float(scal[0]) + 1e-8f);

    {
        const int ic = tid >> 2, g = tid & 3;
        const float* __restrict__ src =
            x + (((size_t)n * CC + ic) * HH + y) * WW + s * 64 + g * 16;
        unsigned dw[4];
        #pragma unroll
        for (int q = 0; q < 4; ++q) {
            float4 v = *(const float4*)(src + q * 4);
            float e[4] = {v.x, v.y, v.z, v.w};
            unsigned d = 0;
            #pragma unroll
            for (int j = 0; j < 4; ++j) {
                int qq = (int)rintf(fminf(fmaxf(e[j] * inv_s1, -1.f), 1.f));
                d |= (unsigned)(qq & 255) << (8 * j);
            }
            dw[q] = d;
        }
        *(int4*)(ldsA + ic * 68 + g * 16) = *(const int4*)dw;
    }
    __syncthreads();
    #pragma unroll
    for (int i = 0; i < 4; ++i) {
        int idx = tid + i * 256;
        int d = idx & 15, p = idx >> 4;
        const signed char* a = ldsA + (d * 4) * 68 + p;
        unsigned b0 = (unsigned char)a[0];
        unsigned b1 = (unsigned char)a[68];
        unsigned b2 = (unsigned char)a[136];
        unsigned b3 = (unsigned char)a[204];
        ldsB[p * 16 + d] = (int)(b0 | (b1 << 8) | (b2 << 16) | (b3 << 24));
    }
    __syncthreads();
    signed char* dst = xq + ((size_t)n * PYY + (y + 1)) * (PXX * 64)
                          + (size_t)(1 + s * 64) * 64;
    ((int4*)dst)[tid] = ((const int4*)ldsB)[tid];
}

// ---------------- conv1: barrier-free streaming MFMA -> pixel-major int16 acc ----------
// A = activations (M = 16 consecutive x), B = weights (N = 16 oc).
// acc16 layout: [n][y][x][64 oc] int16 -> wave writes merge to full lines in L2.
__global__ __launch_bounds__(512, 5) void k_conv1(
    const signed char* __restrict__ xq,
    const signed char* __restrict__ w8,
    const float* __restrict__ bias,       // b1 (for relu-max only)
    unsigned* __restrict__ scal,
    short* __restrict__ accout)
{
    __shared__ float redm[8];
    const int tid = threadIdx.x;
    const int n   = blockIdx.z;
    const int oy0 = blockIdx.y * TR;
    const int ox0 = blockIdx.x * TC;
    const float s1 = __uint_as_float(scal[0]) + 1e-8f;

    const int w     = tid >> 6;
    const int lane  = tid & 63;
    const int lq    = lane >> 4;
    const int lc    = lane & 15;
    const int mH    = w & 1;
    const int rbase = (w >> 1) * 4;       // 4 row-bands x 4 rows = 16 rows

    const signed char* __restrict__ A0 = xq + (size_t)n * XQIMG
        + ((size_t)(oy0 + rbase) * PXX + ox0 + lc) * 64 + lq * 16;
    const signed char* __restrict__ W0 = w8 + ((size_t)mH * 18 * 64 + lane) * 16;

    int32x4 acc0[4] = {};
    int32x4 acc1[4] = {};
    #pragma unroll 3
    for (int tap = 0; tap < 9; ++tap) {
        const int ky = tap / 3, kx = tap % 3;
        int32x4 b0 = *(const int32x4*)(W0 + (size_t)tap * 1024);
        int32x4 b1 = *(const int32x4*)(W0 + (size_t)(9 + tap) * 1024);
        const signed char* ar = A0 + (ky * PXX + kx) * 64;
        #pragma unroll
        for (int j = 0; j < 4; ++j) {
            int32x4 a = *(const int32x4*)(ar + j * (PXX * 64));
            acc0[j] = __builtin_amdgcn_mfma_i32_16x16x64_i8(a, b0, acc0[j], 0, 0, 0);
            acc1[j] = __builtin_amdgcn_mfma_i32_16x16x64_i8(a, b1, acc1[j], 0, 0, 0);
        }
    }

    // epilogue: pixel-major int16 store + slotted atomic relu-max
    const float sc = s1 * (1.f / 3.f);
    const int oc0 = mH * 32 + lc;
    const int oc1 = oc0 + 16;
    const float bo0 = bias[oc0], bo1 = bias[oc1];

    // lane base: pixel (oy0+rbase, ox0+lq*4), channel offset oc0/oc1
    const size_t abase = (((size_t)n * HH + (oy0 + rbase)) * WW + (ox0 + lq * 4)) * 64;

    float m2 = 0.f;
    #pragma unroll
    for (int j = 0; j < 4; ++j) {
        #pragma unroll
        for (int g = 0; g < 4; ++g) {
            int v0 = acc0[j][g], v1 = acc1[j][g];
            m2 = fmaxf(m2, sc * (float)v0 + bo0);
            m2 = fmaxf(m2, sc * (float)v1 + bo1);
            size_t a = abase + ((size_t)j * WW + g) * 64;
            accout[a + oc0] = (short)v0;
            accout[a + oc1] = (short)v1;
        }
    }
    #pragma unroll
    for (int o = 32; o; o >>= 1) m2 = fmaxf(m2, __shfl_down(m2, o, 64));
    if (lane == 0) redm[w] = m2;
    __syncthreads();
    if (tid == 0) {
        float v = redm[0];
        #pragma unroll
        for (int i = 1; i < 8; ++i) v = fmaxf(v, redm[i]);
        int slot = (blockIdx.x + blockIdx.y * 8 + blockIdx.z) & 7;
        atomicMax(&scal[64 + slot * 32], __float_as_uint(v));
    }
}

// ---------------- conv2: coalesced binarize-stage (pixel-major acc16) + MFMA --------
__global__ __launch_bounds__(512, 5) void k_conv2(
    const float* __restrict__ x,
    const short* __restrict__ accin,      // pixel-major [n][y][x][64]
    const signed char* __restrict__ w8,
    const float* __restrict__ bias,       // b2
    const float* __restrict__ b1v,        // b1 (dequant of acc)
    const unsigned* __restrict__ scal,
    float* __restrict__ out)
{
    __shared__ signed char sA[HPX * 64] __attribute__((aligned(16)));   // 20736 B

    const int tid = threadIdx.x;
    const int n   = blockIdx.z;
    const int oy0 = blockIdx.y * TR;
    const int ox0 = blockIdx.x * TC;

    const float s1 = __uint_as_float(scal[0]) + 1e-8f;
    float mx = 0.f;
    #pragma unroll
    for (int i = 0; i < 8; ++i) mx = fmaxf(mx, __uint_as_float(scal[64 + i * 32]));
    const float s2v = mx + 1e-8f;
    const float half_s2 = 0.5f * s2v;
    const float sc1 = s1 * (1.f / 3.f);

    // stage: one halo pixel per task, 128B contiguous read, binarize 64 ch
    for (int t = tid; t < HPX; t += 512) {
        const int r = t / HC, c = t - r * HC;
        const int y  = oy0 - 1 + r;
        const int xx = ox0 - 1 + c;
        unsigned pk[16];
        #pragma unroll
        for (int d = 0; d < 16; ++d) pk[d] = 0;
        if (y >= 0 && y < HH && xx >= 0 && xx < WW) {
            const short8_t* __restrict__ ap =
                (const short8_t*)(accin + (((size_t)n * HH + y) * WW + xx) * 64);
            #pragma unroll
            for (int k = 0; k < 8; ++k) {
                short8_t sv = ap[k];
                float4 bA = *(const float4*)(b1v + k * 8);
                float4 bB = *(const float4*)(b1v + k * 8 + 4);
                float ba[8] = {bA.x, bA.y, bA.z, bA.w, bB.x, bB.y, bB.z, bB.w};
                #pragma unroll
                for (int e = 0; e < 8; ++e) {
                    float fv = sc1 * (float)sv[e] + ba[e];
                    if (fv >= half_s2) pk[2 * k + (e >> 2)] |= 1u << ((e & 3) * 8);
                }
            }
        }
        #pragma unroll
        for (int q = 0; q < 4; ++q) {
            int4 wv;
            wv.x = (int)pk[4 * q];     wv.y = (int)pk[4 * q + 1];
            wv.z = (int)pk[4 * q + 2]; wv.w = (int)pk[4 * q + 3];
            *(int4*)(sA + lds_a(t, q)) = wv;
        }
    }
    __syncthreads();

    const int w     = tid >> 6;
    const int lane  = tid & 63;
    const int lq    = lane >> 4;
    const int lc    = lane & 15;
    const int mH    = w & 1;
    const int rbase = (w >> 1) * 4;
    const signed char* __restrict__ W0 = w8 + ((size_t)mH * 18 * 64 + lane) * 16;

    int32x4 acc0[4] = {};
    int32x4 acc1[4] = {};
    __builtin_amdgcn_s_setprio(1);
    #pragma unroll 3
    for (int tap = 0; tap < 9; ++tap) {
        const int ky = tap / 3, kx = tap % 3;
        int32x4 b0 = *(const int32x4*)(W0 + (size_t)tap * 1024);
        int32x4 b1 = *(const int32x4*)(W0 + (size_t)(9 + tap) * 1024);
        #pragma unroll
        for (int j = 0; j < 4; ++j) {
            int pix = (rbase + j + ky) * HC + kx + lc;
            int32x4 a = *(const int32x4*)(sA + lds_a(pix, lq));
            acc0[j] = __builtin_amdgcn_mfma_i32_16x16x64_i8(a, b0, acc0[j], 0, 0, 0);
            acc1[j] = __builtin_amdgcn_mfma_i32_16x16x64_i8(a, b1, acc1[j], 0, 0, 0);
        }
    }
    __builtin_amdgcn_s_setprio(0);

    const float sc = s2v * (1.f / 3.f);
    const int oc0 = mH * 32 + lc;
    const int oc1 = oc0 + 16;
    const float bo0 = bias[oc0], bo1 = bias[oc1];
    const size_t imgbase = (size_t)n * CC * PL;

    #pragma unroll
    for (int j = 0; j < 4; ++j) {
        int yy = oy0 + rbase + j;
        int xb = ox0 + lq * 4;
        size_t p0 = imgbase + (size_t)oc0 * PL + yy * WW + xb;
        size_t p1 = imgbase + (size_t)oc1 * PL + yy * WW + xb;
        float4 xa  = *(const float4*)(x + p0);
        float4 xb4 = *(const float4*)(x + p1);
        float4 r0, r1;
        r0.x = sc * (float)acc0[j][0] + bo0 + xa.x;
        r0.y = sc * (float)acc0[j][1] + bo0 + xa.y;
        r0.z = sc * (float)acc0[j][2] + bo0 + xa.z;
        r0.w = sc * (float)acc0[j][3] + bo0 + xa.w;
        r1.x = sc * (float)acc1[j][0] + bo1 + xb4.x;
        r1.y = sc * (float)acc1[j][1] + bo1 + xb4.y;
        r1.z = sc * (float)acc1[j][2] + bo1 + xb4.z;
        r1.w = sc * (float)acc1[j][3] + bo1 + xb4.w;
        *(float4*)(out + p0) = r0;
        *(float4*)(out + p1) = r1;
    }
}

extern "C" void kernel_launch(void* const* d_in, const int* in_sizes, int n_in,
                              void* d_out, int out_size, void* d_ws, size_t ws_size,
                              hipStream_t stream) {
    const float* x  = (const float*)d_in[0];
    const float* w1 = (const float*)d_in[1];
    const float* b1 = (const float*)d_in[2];
    const float* w2 = (const float*)d_in[3];
    const float* b2 = (const float*)d_in[4];
    float* out = (float*)d_out;

    // ws layout
    unsigned*    scal  = (unsigned*)d_ws;                  // [0]=s1; s2 slots at [64+i*32]
    signed char* w8_1  = (signed char*)d_ws + 2048;        // 36864 B
    signed char* w8_2  = w8_1 + WELEM;                     // 36864 B
    short*       acc16 = (short*)((char*)d_ws + 131072);   // 33.55 MB pixel-major
    // xq lives in d_out's scratch space: written by k_quantx, read only by
    // k_conv1, fully overwritten by k_conv2's final output.
    signed char* xq    = (signed char*)d_out;

    hipMemsetAsync(d_ws, 0, 2048, stream);
    hipMemsetAsync(d_out, 0, XQTOT, stream);   // zero padded borders of xq

    k_reduce<<<258, 1024, 0, stream>>>(x, w1, w2, scal, w8_1, w8_2);
    k_quantx<<<dim3(2, HH, NB), 256, 0, stream>>>(x, scal, xq);

    dim3 grid(WW / TC, HH / TR, NB);   // (8, 8, 16)
    k_conv1<<<grid, 512, 0, stream>>>(xq, w8_1, b1, scal, acc16);
    k_conv2<<<grid, 512, 0, stream>>>(x, acc16, w8_2, b2, b1, scal, out);
}